// Round 1
// baseline (1261.922 us; speedup 1.0000x reference)
//
#include <hip/hip_runtime.h>
#include <stdint.h>

#define D 1024
#define N 200000
#define C 50
#define B 4096
#define CLS 4

// workspace layout (float offsets)
static const size_t OFF_DOTS = 0;                       // C*N
static const size_t OFF_TESQ = (size_t)C * N;           // N
static const size_t OFF_GRAM = OFF_TESQ + N;            // C*C
static const size_t OFF_INV  = OFF_GRAM + C * C;        // C*C
static const size_t OFF_CSQ  = OFF_INV + C * C;         // C
static const size_t OFF_WC   = OFF_CSQ + C;             // CLS*C
static const size_t OFF_SUMS = OFF_WC + CLS * C;        // C

__device__ __forceinline__ unsigned mapf(float v) {
    unsigned u = __float_as_uint(v);
    return (u & 0x80000000u) ? ~u : (u | 0x80000000u);
}

__device__ __forceinline__ float dist2_of(float csq, float tesq, float dot) {
    // fixed instruction sequence so histogram & sum passes agree bit-exactly
    return fmaf(-2.0f, dot, csq + tesq);
}

__device__ __forceinline__ float blk_reduce_1024(float v, float* red, int t) {
    #pragma unroll
    for (int off = 32; off > 0; off >>= 1) v += __shfl_down(v, off, 64);
    __syncthreads();
    if ((t & 63) == 0) red[t >> 6] = v;
    __syncthreads();
    if (t == 0) { float s = 0.f; for (int w = 0; w < 16; ++w) s += red[w]; red[0] = s; }
    __syncthreads();
    return red[0];
}

// ---------------- K1: gram, scalars, inverse, wc -----------------
__global__ __launch_bounds__(1024) void k1_gram_inv(
    const float* __restrict__ concept, const float* __restrict__ hxw,
    float* __restrict__ ws, float* __restrict__ out)
{
    __shared__ __align__(16) float ct[64 * 50];   // concept d-tile
    __shared__ float gram[C * C];
    __shared__ float M[C * 100];                  // [A | I] for Gauss-Jordan
    __shared__ float red[16];
    __shared__ float colp[C];
    __shared__ int   piv;

    int t = threadIdx.x;

    // gram = concept^T concept via d-tiles of 64
    float g[3] = {0.f, 0.f, 0.f};
    for (int d0 = 0; d0 < D; d0 += 64) {
        __syncthreads();
        for (int i = t; i < 64 * 50; i += 1024) ct[i] = concept[d0 * 50 + i];
        __syncthreads();
        #pragma unroll
        for (int s = 0; s < 3; ++s) {
            int p = t + s * 1024;
            if (p < C * C) {
                int i = p / C, j = p % C;
                float acc = g[s];
                for (int dd = 0; dd < 64; ++dd)
                    acc = fmaf(ct[dd * 50 + i], ct[dd * 50 + j], acc);
                g[s] = acc;
            }
        }
    }
    __syncthreads();
    #pragma unroll
    for (int s = 0; s < 3; ++s) {
        int p = t + s * 1024;
        if (p < C * C) gram[p] = g[s];
    }
    __syncthreads();

    // persist gram + diagonal
    for (int p = t; p < C * C; p += 1024) ws[OFF_GRAM + p] = gram[p];
    if (t < C) ws[OFF_CSQ + t] = gram[t * C + t];

    // scalar metrics
    float s_all = 0.f, s_tr = 0.f, s_abs = 0.f;
    for (int p = t; p < C * C; p += 1024) {
        float v = gram[p];
        int i = p / C, j = p % C;
        float e = (i == j) ? 1.0f : 0.0f;
        s_all += v;
        if (i == j) s_tr += v;
        s_abs += fabsf(v - e);
    }
    float tot_all = blk_reduce_1024(s_all, red, t);
    float tot_tr  = blk_reduce_1024(s_tr,  red, t);
    float tot_abs = blk_reduce_1024(s_abs, red, t);
    if (t == 0) {
        out[32769] = (tot_all - tot_tr) / 2500.0f;  // L_sparse_2
        out[32770] = tot_tr / 2500.0f;              // norm_metrics
        out[32771] = tot_abs / 2500.0f;             // similarity_penalty
    }

    // wc[cls][c] = sum_d hxw[cls,d] * concept[d,c]
    if (t < CLS * C) {
        int cls = t / C, c = t % C;
        float acc = 0.f;
        for (int d = 0; d < D; ++d)
            acc = fmaf(hxw[cls * D + d], concept[d * C + c], acc);
        ws[OFF_WC + cls * C + c] = acc;
    }

    // Gauss-Jordan inversion with partial pivoting
    __syncthreads();
    for (int p = t; p < C * 100; p += 1024) {
        int r = p / 100, j = p % 100;
        M[p] = (j < C) ? gram[r * C + j] : ((j - C) == r ? 1.0f : 0.0f);
    }
    __syncthreads();
    for (int pc = 0; pc < C; ++pc) {
        if (t == 0) {
            int best = pc; float bv = fabsf(M[pc * 100 + pc]);
            for (int r = pc + 1; r < C; ++r) {
                float v = fabsf(M[r * 100 + pc]);
                if (v > bv) { bv = v; best = r; }
            }
            piv = best;
        }
        __syncthreads();
        int pr = piv;
        if (pr != pc && t < 100) {
            float tmp = M[pc * 100 + t]; M[pc * 100 + t] = M[pr * 100 + t]; M[pr * 100 + t] = tmp;
        }
        __syncthreads();
        float pinv = 1.0f / M[pc * 100 + pc];
        if (t < C) colp[t] = M[t * 100 + pc];
        __syncthreads();
        if (t < 100) M[pc * 100 + t] *= pinv;
        __syncthreads();
        for (int p = t; p < C * 100; p += 1024) {
            int r = p / 100, j = p % 100;
            if (r != pc) M[r * 100 + j] = fmaf(-colp[r], M[pc * 100 + j], M[r * 100 + j]);
        }
        __syncthreads();
    }
    for (int p = t; p < C * C; p += 1024) {
        int r = p / C, j = p % C;
        ws[OFF_INV + p] = M[r * 100 + 50 + j];
    }
}

// ---------------- K2: orig_pred + y_pred -----------------
__global__ __launch_bounds__(256) void k2_pred(
    const float* __restrict__ concept, const float* __restrict__ X,
    const float* __restrict__ hxw, const float* __restrict__ hxb,
    const float* __restrict__ ws, float* __restrict__ out)
{
    __shared__ __align__(16) float xs[8 * 1024];
    __shared__ float t1[8 * C];
    __shared__ float t2[8 * C];

    int t = threadIdx.x;
    int b0 = blockIdx.x * 8;

    const float4* xg = (const float4*)(X + (size_t)b0 * D);
    float4* xsv = (float4*)xs;
    for (int i = t; i < 8 * 256; i += 256) xsv[i] = xg[i];
    __syncthreads();

    // orig_pred
    {
        int b = t >> 5, lane = t & 31;
        #pragma unroll
        for (int cls = 0; cls < CLS; ++cls) {
            float acc = 0.f;
            for (int d = lane; d < D; d += 32)
                acc = fmaf(xs[b * D + d], hxw[cls * D + d], acc);
            #pragma unroll
            for (int off = 16; off > 0; off >>= 1) acc += __shfl_down(acc, off, 32);
            if (lane == 0) out[(size_t)(b0 + b) * CLS + cls] = acc + hxb[cls];
        }
    }

    // t1[b][c] = concept[:,c] . x_b
    for (int p = t; p < 8 * C; p += 256) {
        int b = p / C, c = p % C;
        float acc = 0.f;
        for (int d = 0; d < D; ++d)
            acc = fmaf(xs[b * D + d], concept[d * C + c], acc);
        t1[p] = acc;
    }
    __syncthreads();
    // t2 = inv @ t1
    for (int p = t; p < 8 * C; p += 256) {
        int b = p / C, c = p % C;
        float acc = 0.f;
        for (int cc = 0; cc < C; ++cc)
            acc = fmaf(ws[OFF_INV + c * C + cc], t1[b * C + cc], acc);
        t2[p] = acc;
    }
    __syncthreads();
    // y_pred[b][cls] = wc[cls,:] . t2[b,:] + bias
    if (t < 8 * CLS) {
        int b = t >> 2, cls = t & 3;
        float acc = 0.f;
        for (int c = 0; c < C; ++c)
            acc = fmaf(ws[OFF_WC + cls * C + c], t2[b * C + c], acc);
        out[16384 + (size_t)(b0 + b) * CLS + cls] = acc + hxb[cls];
    }
}

// ---------------- K3: dots + te_sq (the big one) -----------------
#define TD 128
__global__ __launch_bounds__(256) void k3_dots(
    const float* __restrict__ concept, const float* __restrict__ te,
    float* __restrict__ ws)
{
    __shared__ __align__(16) float cs[TD * 52];   // padded rows: 52 floats = 208B (16B aligned)
    int t = threadIdx.x;
    int n = blockIdx.x * 256 + t;
    bool active = (n < N);

    float acc[50];
    #pragma unroll
    for (int c = 0; c < 50; ++c) acc[c] = 0.f;
    float tesq = 0.f;

    for (int d0 = 0; d0 < D; d0 += TD) {
        __syncthreads();
        for (int i = t; i < TD * 50; i += 256) {
            int dd = i / 50, c = i - dd * 50;
            cs[dd * 52 + c] = concept[d0 * 50 + i];
        }
        __syncthreads();
        if (active) {
            #pragma unroll 2
            for (int dd = 0; dd < TD; ++dd) {
                float x = te[(size_t)(d0 + dd) * N + n];
                tesq = fmaf(x, x, tesq);
                const float4* cr = (const float4*)&cs[dd * 52];
                #pragma unroll
                for (int q = 0; q < 12; ++q) {
                    float4 cv = cr[q];
                    acc[q * 4 + 0] = fmaf(x, cv.x, acc[q * 4 + 0]);
                    acc[q * 4 + 1] = fmaf(x, cv.y, acc[q * 4 + 1]);
                    acc[q * 4 + 2] = fmaf(x, cv.z, acc[q * 4 + 2]);
                    acc[q * 4 + 3] = fmaf(x, cv.w, acc[q * 4 + 3]);
                }
                float2 cv2 = *(const float2*)&cs[dd * 52 + 48];
                acc[48] = fmaf(x, cv2.x, acc[48]);
                acc[49] = fmaf(x, cv2.y, acc[49]);
            }
        }
    }
    if (active) {
        #pragma unroll
        for (int c = 0; c < 50; ++c) ws[(size_t)c * N + n] = acc[c];
        ws[OFF_TESQ + n] = tesq;
    }
}

// ---------------- K4: exact top-k select + dot-sum per concept -----------------
__global__ __launch_bounds__(1024) void k4_select(
    const float* __restrict__ ws_r, float* __restrict__ ws_w,
    const int* __restrict__ topk)
{
    int c = blockIdx.x;
    int t = threadIdx.x;
    int k = *topk;

    const float* dots = ws_r + (size_t)c * N;
    const float* tesq = ws_r + OFF_TESQ;
    float csq = ws_r[OFF_CSQ + c];

    __shared__ unsigned hist[4096];
    __shared__ unsigned sums[1024];
    __shared__ float fred[16];
    __shared__ int tieidx[1024];
    __shared__ int tiecnt;
    __shared__ unsigned sh_prefix;
    __shared__ int sh_remaining;

    unsigned prefix = 0;
    int remaining = k;

    #pragma unroll 1
    for (int pass = 0; pass < 3; ++pass) {
        int shift = (pass == 0) ? 20 : (pass == 1) ? 8 : 0;
        int bins  = (pass == 2) ? 256 : 4096;
        unsigned himask = (pass == 0) ? 0u : (pass == 1) ? 0xFFF00000u : 0xFFFFFF00u;

        for (int i = t; i < 4096; i += 1024) hist[i] = 0u;
        __syncthreads();
        for (int n = t; n < N; n += 1024) {
            float d2 = dist2_of(csq, tesq[n], dots[n]);
            unsigned u = mapf(d2);
            if ((u & himask) == prefix)
                atomicAdd(&hist[(u >> shift) & (bins - 1)], 1u);
        }
        __syncthreads();
        unsigned s4 = 0;
        if (t * 4 < bins)
            s4 = hist[t * 4] + hist[t * 4 + 1] + hist[t * 4 + 2] + hist[t * 4 + 3];
        sums[t] = s4;
        __syncthreads();
        if (t == 0) {
            unsigned rem = (unsigned)remaining;
            unsigned cum = 0;
            int nb = bins >> 2;
            int ci = 0;
            while (ci < nb && cum + sums[ci] < rem) { cum += sums[ci]; ++ci; }
            int bin = ci << 2;
            while (cum + hist[bin] < rem) { cum += hist[bin]; ++bin; }
            sh_prefix = prefix | ((unsigned)bin << shift);
            sh_remaining = (int)(rem - cum);
        }
        __syncthreads();
        prefix = sh_prefix;
        remaining = sh_remaining;
        __syncthreads();
    }

    // final pass: sum dots strictly below threshold; collect ties
    if (t == 0) tiecnt = 0;
    __syncthreads();
    float lsum = 0.f;
    for (int n = t; n < N; n += 1024) {
        float d2 = dist2_of(csq, tesq[n], dots[n]);
        unsigned u = mapf(d2);
        if (u < prefix) lsum += dots[n];
        else if (u == prefix) {
            int slot = atomicAdd(&tiecnt, 1);
            if (slot < 1024) tieidx[slot] = n;
        }
    }
    __syncthreads();
    float total = blk_reduce_1024(lsum, fred, t);
    if (t == 0) {
        int cnt = tiecnt; if (cnt > 1024) cnt = 1024;
        int r = remaining; if (r > cnt) r = cnt;
        float tsum = 0.f;
        for (int taken = 0; taken < r; ++taken) {
            int bi = -1, bv = 0x7FFFFFFF;
            for (int i = 0; i < cnt; ++i) {
                int v = tieidx[i];
                if (v >= 0 && v < bv) { bv = v; bi = i; }
            }
            if (bi >= 0) { tsum += dots[bv]; tieidx[bi] = -1; }
        }
        ws_w[OFF_SUMS + c] = total + tsum;
    }
}

// ---------------- K5: L_sparse_1 -----------------
__global__ void k5_final(const float* __restrict__ ws, float* __restrict__ out,
                         const int* __restrict__ topk)
{
    if (threadIdx.x == 0 && blockIdx.x == 0) {
        float s = 0.f;
        for (int c = 0; c < C; ++c) s += ws[OFF_SUMS + c];
        int k = *topk;
        out[32768] = s / (float)(k * C);
    }
}

extern "C" void kernel_launch(void* const* d_in, const int* in_sizes, int n_in,
                              void* d_out, int out_size, void* d_ws, size_t ws_size,
                              hipStream_t stream) {
    (void)in_sizes; (void)n_in; (void)out_size; (void)ws_size;
    const float* concept = (const float*)d_in[0];
    const float* te      = (const float*)d_in[1];
    const float* X       = (const float*)d_in[2];
    const float* hxw     = (const float*)d_in[3];
    const float* hxb     = (const float*)d_in[4];
    const int*   topk    = (const int*)d_in[5];
    float* out = (float*)d_out;
    float* ws  = (float*)d_ws;

    k3_dots<<<dim3((N + 255) / 256), dim3(256), 0, stream>>>(concept, te, ws);
    k1_gram_inv<<<dim3(1), dim3(1024), 0, stream>>>(concept, hxw, ws, out);
    k2_pred<<<dim3(B / 8), dim3(256), 0, stream>>>(concept, X, hxw, hxb, ws, out);
    k4_select<<<dim3(C), dim3(1024), 0, stream>>>(ws, ws, topk);
    k5_final<<<dim3(1), dim3(1), 0, stream>>>(ws, out, topk);
}

// Round 2
// 865.012 us; speedup vs baseline: 1.4588x; 1.4588x over previous
//
#include <hip/hip_runtime.h>
#include <stdint.h>

#define D 1024
#define N 200000
#define C 50
#define B 4096
#define CLS 4
#define NCHUNK 8
#define CHUNK (N / NCHUNK)   // 25000

// workspace layout (float offsets)
static const size_t OFF_DOTS = 0;                        // C*N
static const size_t OFF_TESQ = (size_t)C * N;            // N
static const size_t OFF_GRAM = OFF_TESQ + N;             // C*C
static const size_t OFF_INV  = OFF_GRAM + C * C;         // C*C
static const size_t OFF_CSQ  = OFF_INV + C * C;          // C
static const size_t OFF_WC   = OFF_CSQ + C;              // CLS*C
static const size_t OFF_SUMS = OFF_WC + CLS * C;         // C   (float, atomic)
static const size_t OFF_HIST = OFF_SUMS + C;             // C*4096 (uint)
static const size_t OFF_PREF = OFF_HIST + (size_t)C * 4096;  // C (uint)
static const size_t OFF_REM  = OFF_PREF + C;             // C (int)
static const size_t OFF_TIEC = OFF_REM + C;              // C (int)
static const size_t OFF_TIEI = OFF_TIEC + C;             // C*64 (int)

__device__ __forceinline__ unsigned mapf(float v) {
    unsigned u = __float_as_uint(v);
    return (u & 0x80000000u) ? ~u : (u | 0x80000000u);
}

__device__ __forceinline__ float dist2_of(float csq, float tesq, float dot) {
    // fixed instruction sequence so all passes agree bit-exactly
    return fmaf(-2.0f, dot, csq + tesq);
}

__device__ __forceinline__ float blk_reduce_1024(float v, float* red, int t) {
    #pragma unroll
    for (int off = 32; off > 0; off >>= 1) v += __shfl_down(v, off, 64);
    __syncthreads();
    if ((t & 63) == 0) red[t >> 6] = v;
    __syncthreads();
    if (t == 0) { float s = 0.f; for (int w = 0; w < 16; ++w) s += red[w]; red[0] = s; }
    __syncthreads();
    return red[0];
}

// ---------------- K1: gram, scalars, inverse, wc -----------------
__global__ __launch_bounds__(1024) void k1_gram_inv(
    const float* __restrict__ concept, const float* __restrict__ hxw,
    float* __restrict__ ws, float* __restrict__ out)
{
    __shared__ __align__(16) float ct[64 * 50];
    __shared__ float gram[C * C];
    __shared__ float M[C * 100];
    __shared__ float red[16];
    __shared__ float colp[C];
    __shared__ int   piv;

    int t = threadIdx.x;

    float g[3] = {0.f, 0.f, 0.f};
    for (int d0 = 0; d0 < D; d0 += 64) {
        __syncthreads();
        for (int i = t; i < 64 * 50; i += 1024) ct[i] = concept[d0 * 50 + i];
        __syncthreads();
        #pragma unroll
        for (int s = 0; s < 3; ++s) {
            int p = t + s * 1024;
            if (p < C * C) {
                int i = p / C, j = p % C;
                float acc = g[s];
                for (int dd = 0; dd < 64; ++dd)
                    acc = fmaf(ct[dd * 50 + i], ct[dd * 50 + j], acc);
                g[s] = acc;
            }
        }
    }
    __syncthreads();
    #pragma unroll
    for (int s = 0; s < 3; ++s) {
        int p = t + s * 1024;
        if (p < C * C) gram[p] = g[s];
    }
    __syncthreads();

    for (int p = t; p < C * C; p += 1024) ws[OFF_GRAM + p] = gram[p];
    if (t < C) ws[OFF_CSQ + t] = gram[t * C + t];

    float s_all = 0.f, s_tr = 0.f, s_abs = 0.f;
    for (int p = t; p < C * C; p += 1024) {
        float v = gram[p];
        int i = p / C, j = p % C;
        float e = (i == j) ? 1.0f : 0.0f;
        s_all += v;
        if (i == j) s_tr += v;
        s_abs += fabsf(v - e);
    }
    float tot_all = blk_reduce_1024(s_all, red, t);
    float tot_tr  = blk_reduce_1024(s_tr,  red, t);
    float tot_abs = blk_reduce_1024(s_abs, red, t);
    if (t == 0) {
        out[32769] = (tot_all - tot_tr) / 2500.0f;
        out[32770] = tot_tr / 2500.0f;
        out[32771] = tot_abs / 2500.0f;
    }

    if (t < CLS * C) {
        int cls = t / C, c = t % C;
        float acc = 0.f;
        for (int d = 0; d < D; ++d)
            acc = fmaf(hxw[cls * D + d], concept[d * C + c], acc);
        ws[OFF_WC + cls * C + c] = acc;
    }

    __syncthreads();
    for (int p = t; p < C * 100; p += 1024) {
        int r = p / 100, j = p % 100;
        M[p] = (j < C) ? gram[r * C + j] : ((j - C) == r ? 1.0f : 0.0f);
    }
    __syncthreads();
    for (int pc = 0; pc < C; ++pc) {
        if (t < 64) {
            float av = -1.f; int ai = pc;
            if (t < C && t >= pc) { av = fabsf(M[t * 100 + pc]); ai = t; }
            #pragma unroll
            for (int off = 32; off > 0; off >>= 1) {
                float ov = __shfl_down(av, off, 64);
                int   oi = __shfl_down(ai, off, 64);
                if (ov > av) { av = ov; ai = oi; }
            }
            if (t == 0) piv = ai;
        }
        __syncthreads();
        int pr = piv;
        if (pr != pc && t < 100) {
            float tmp = M[pc * 100 + t]; M[pc * 100 + t] = M[pr * 100 + t]; M[pr * 100 + t] = tmp;
        }
        __syncthreads();
        float pinv = 1.0f / M[pc * 100 + pc];
        if (t < C) colp[t] = M[t * 100 + pc];
        __syncthreads();
        if (t < 100) M[pc * 100 + t] *= pinv;
        __syncthreads();
        for (int p = t; p < C * 100; p += 1024) {
            int r = p / 100, j = p % 100;
            if (r != pc) M[r * 100 + j] = fmaf(-colp[r], M[pc * 100 + j], M[r * 100 + j]);
        }
        __syncthreads();
    }
    for (int p = t; p < C * C; p += 1024) {
        int r = p / C, j = p % C;
        ws[OFF_INV + p] = M[r * 100 + 50 + j];
    }
}

// ---------------- K2: orig_pred + y_pred -----------------
__global__ __launch_bounds__(256) void k2_pred(
    const float* __restrict__ concept, const float* __restrict__ X,
    const float* __restrict__ hxw, const float* __restrict__ hxb,
    const float* __restrict__ ws, float* __restrict__ out)
{
    __shared__ __align__(16) float xs[8 * 1024];
    __shared__ float t1[8 * C];
    __shared__ float t2[8 * C];

    int t = threadIdx.x;
    int b0 = blockIdx.x * 8;

    const float4* xg = (const float4*)(X + (size_t)b0 * D);
    float4* xsv = (float4*)xs;
    for (int i = t; i < 8 * 256; i += 256) xsv[i] = xg[i];
    __syncthreads();

    {
        int b = t >> 5, lane = t & 31;
        #pragma unroll
        for (int cls = 0; cls < CLS; ++cls) {
            float acc = 0.f;
            for (int d = lane; d < D; d += 32)
                acc = fmaf(xs[b * D + d], hxw[cls * D + d], acc);
            #pragma unroll
            for (int off = 16; off > 0; off >>= 1) acc += __shfl_down(acc, off, 32);
            if (lane == 0) out[(size_t)(b0 + b) * CLS + cls] = acc + hxb[cls];
        }
    }

    for (int p = t; p < 8 * C; p += 256) {
        int b = p / C, c = p % C;
        float acc = 0.f;
        for (int d = 0; d < D; ++d)
            acc = fmaf(xs[b * D + d], concept[d * C + c], acc);
        t1[p] = acc;
    }
    __syncthreads();
    for (int p = t; p < 8 * C; p += 256) {
        int b = p / C, c = p % C;
        float acc = 0.f;
        for (int cc = 0; cc < C; ++cc)
            acc = fmaf(ws[OFF_INV + c * C + cc], t1[b * C + cc], acc);
        t2[p] = acc;
    }
    __syncthreads();
    if (t < 8 * CLS) {
        int b = t >> 2, cls = t & 3;
        float acc = 0.f;
        for (int c = 0; c < C; ++c)
            acc = fmaf(ws[OFF_WC + cls * C + c], t2[b * C + c], acc);
        out[16384 + (size_t)(b0 + b) * CLS + cls] = acc + hxb[cls];
    }
}

// ---------------- K3: dots + te_sq — no LDS, deep load pipelining -----------------
__global__ __launch_bounds__(256) void k3_dots(
    const float* __restrict__ concept, const float* __restrict__ te,
    float* __restrict__ ws)
{
    int n = blockIdx.x * 256 + threadIdx.x;
    if (n >= N) return;   // no barriers in this kernel — early exit safe

    float acc[50];
    #pragma unroll
    for (int c = 0; c < 50; ++c) acc[c] = 0.f;
    float tesq = 0.f;

    const float* tp = te + n;

    for (int d0 = 0; d0 < D; d0 += 8) {
        float x[8];
        #pragma unroll
        for (int u = 0; u < 8; ++u)
            x[u] = tp[(size_t)(d0 + u) * N];
        #pragma unroll
        for (int u = 0; u < 8; ++u) {
            tesq = fmaf(x[u], x[u], tesq);
            const float* crow = concept + (d0 + u) * 50;  // wave-uniform → scalar/broadcast loads
            #pragma unroll
            for (int c = 0; c < 50; ++c)
                acc[c] = fmaf(x[u], crow[c], acc[c]);
        }
    }

    #pragma unroll
    for (int c = 0; c < 50; ++c) ws[(size_t)c * N + n] = acc[c];
    ws[OFF_TESQ + n] = tesq;
}

// ---------------- K4 stage 0: init hist/state -----------------
__global__ __launch_bounds__(256) void k_init(float* __restrict__ ws,
                                              const int* __restrict__ topk)
{
    int c = blockIdx.x, t = threadIdx.x;
    unsigned* gh = (unsigned*)(ws + OFF_HIST) + (size_t)c * 4096;
    for (int i = t; i < 4096; i += 256) gh[i] = 0u;
    if (t == 0) {
        ((unsigned*)(ws + OFF_PREF))[c] = 0u;
        ((int*)(ws + OFF_REM))[c] = *topk;
        ((int*)(ws + OFF_TIEC))[c] = 0;
        ws[OFF_SUMS + c] = 0.f;
    }
}

// ---------------- K4 histogram pass (grid: C x NCHUNK) -----------------
__global__ __launch_bounds__(256) void k_hist(const float* __restrict__ ws,
                                              float* __restrict__ wsw, int pass)
{
    int c = blockIdx.x, chunk = blockIdx.y, t = threadIdx.x;
    int shift = (pass == 0) ? 20 : (pass == 1) ? 8 : 0;
    int bins  = (pass == 2) ? 256 : 4096;
    unsigned himask = (pass == 0) ? 0u : (pass == 1) ? 0xFFF00000u : 0xFFFFFF00u;
    unsigned prefix = ((const unsigned*)(ws + OFF_PREF))[c];

    const float* dots = ws + (size_t)c * N;
    const float* tesq = ws + OFF_TESQ;
    float csq = ws[OFF_CSQ + c];

    __shared__ unsigned h[4096];
    for (int i = t; i < bins; i += 256) h[i] = 0u;
    __syncthreads();

    int n0 = chunk * CHUNK;
    for (int n = n0 + t; n < n0 + CHUNK; n += 256) {
        float d2 = dist2_of(csq, tesq[n], dots[n]);
        unsigned u = mapf(d2);
        if ((u & himask) == prefix)
            atomicAdd(&h[(u >> shift) & (bins - 1)], 1u);
    }
    __syncthreads();
    unsigned* gh = (unsigned*)(wsw + OFF_HIST) + (size_t)c * 4096;
    for (int i = t; i < bins; i += 256) {
        unsigned v = h[i];
        if (v) atomicAdd(&gh[i], v);
    }
}

// ---------------- K4 pick cutoff bin (grid: C, block 1024) -----------------
__global__ __launch_bounds__(1024) void k_pick(float* __restrict__ ws, int pass)
{
    int c = blockIdx.x, t = threadIdx.x;
    int shift = (pass == 0) ? 20 : (pass == 1) ? 8 : 0;
    int bins  = (pass == 2) ? 256 : 4096;

    unsigned* gh = (unsigned*)(ws + OFF_HIST) + (size_t)c * 4096;
    unsigned* pref = (unsigned*)(ws + OFF_PREF);
    int* remp = (int*)(ws + OFF_REM);

    __shared__ unsigned wsum[16], woff[16];
    __shared__ unsigned found_bin;
    __shared__ int found_rem;

    unsigned rem = (unsigned)remp[c];
    unsigned b0 = (unsigned)t * 4;
    unsigned h0 = 0, h1 = 0, h2 = 0, h3 = 0, s4 = 0;
    if (b0 < (unsigned)bins) {
        h0 = gh[b0]; h1 = gh[b0 + 1]; h2 = gh[b0 + 2]; h3 = gh[b0 + 3];
        s4 = h0 + h1 + h2 + h3;
    }
    int lane = t & 63, wid = t >> 6;
    unsigned x = s4;
    #pragma unroll
    for (int off = 1; off < 64; off <<= 1) {
        unsigned y = (unsigned)__shfl_up((int)x, off, 64);
        if (lane >= off) x += y;
    }
    if (lane == 63) wsum[wid] = x;
    __syncthreads();
    if (t == 0) {
        unsigned run = 0;
        for (int w = 0; w < 16; ++w) { woff[w] = run; run += wsum[w]; }
    }
    __syncthreads();
    unsigned cumBefore = woff[wid] + x - s4;
    if (b0 < (unsigned)bins && cumBefore < rem && rem <= cumBefore + s4) {
        unsigned cum = cumBefore, bin = b0, r2 = 1;
        unsigned hh[4] = {h0, h1, h2, h3};
        #pragma unroll
        for (int j = 0; j < 4; ++j) {
            if (cum + hh[j] >= rem) { bin = b0 + j; r2 = rem - cum; break; }
            cum += hh[j];
        }
        found_bin = bin;
        found_rem = (int)r2;
    }
    __syncthreads();
    if (t == 0) {
        pref[c] |= found_bin << shift;
        remp[c] = found_rem;
    }
    for (int i = t; i < bins; i += 1024) gh[i] = 0u;   // ready for next pass
}

// ---------------- K4 final sum + tie collection (grid: C x NCHUNK) -----------------
__global__ __launch_bounds__(256) void k_fsum(const float* __restrict__ ws,
                                              float* __restrict__ wsw)
{
    int c = blockIdx.x, chunk = blockIdx.y, t = threadIdx.x;
    unsigned prefix = ((const unsigned*)(ws + OFF_PREF))[c];
    const float* dots = ws + (size_t)c * N;
    const float* tesq = ws + OFF_TESQ;
    float csq = ws[OFF_CSQ + c];
    int* tiec = (int*)(wsw + OFF_TIEC);
    int* tiei = (int*)(wsw + OFF_TIEI);

    float lsum = 0.f;
    int n0 = chunk * CHUNK;
    for (int n = n0 + t; n < n0 + CHUNK; n += 256) {
        float d2 = dist2_of(csq, tesq[n], dots[n]);
        unsigned u = mapf(d2);
        if (u < prefix) lsum += dots[n];
        else if (u == prefix) {
            int slot = atomicAdd(&tiec[c], 1);
            if (slot < 64) tiei[c * 64 + slot] = n;
        }
    }
    #pragma unroll
    for (int off = 32; off > 0; off >>= 1) lsum += __shfl_down(lsum, off, 64);
    __shared__ float p[4];
    if ((t & 63) == 0) p[t >> 6] = lsum;
    __syncthreads();
    if (t == 0) atomicAdd(&wsw[OFF_SUMS + c], p[0] + p[1] + p[2] + p[3]);
}

// ---------------- K5: resolve ties (lowest index first) + L_sparse_1 -----------------
__global__ __launch_bounds__(64) void k5_final(const float* __restrict__ ws,
                                               float* __restrict__ out,
                                               const int* __restrict__ topk)
{
    __shared__ float persum[64];
    int t = threadIdx.x;
    float v = 0.f;
    if (t < C) {
        int c = t;
        const int* tiei = (const int*)(ws + OFF_TIEI) + c * 64;
        int cnt = ((const int*)(ws + OFF_TIEC))[c]; if (cnt > 64) cnt = 64;
        int r = ((const int*)(ws + OFF_REM))[c];    if (r > cnt) r = cnt;
        int idxs[64];
        for (int i = 0; i < cnt; ++i) idxs[i] = tiei[i];
        float extra = 0.f;
        for (int s = 0; s < r; ++s) {
            int bi = -1, bv = 0x7FFFFFFF;
            for (int i = 0; i < cnt; ++i) {
                int vi = idxs[i];
                if (vi >= 0 && vi < bv) { bv = vi; bi = i; }
            }
            if (bi >= 0) { extra += ws[(size_t)c * N + bv]; idxs[bi] = -1; }
        }
        v = ws[OFF_SUMS + c] + extra;
    }
    persum[t] = v;
    __syncthreads();
    if (t == 0) {
        float s = 0.f;
        for (int i = 0; i < C; ++i) s += persum[i];
        out[32768] = s / (float)((*topk) * C);
    }
}

extern "C" void kernel_launch(void* const* d_in, const int* in_sizes, int n_in,
                              void* d_out, int out_size, void* d_ws, size_t ws_size,
                              hipStream_t stream) {
    (void)in_sizes; (void)n_in; (void)out_size; (void)ws_size;
    const float* concept = (const float*)d_in[0];
    const float* te      = (const float*)d_in[1];
    const float* X       = (const float*)d_in[2];
    const float* hxw     = (const float*)d_in[3];
    const float* hxb     = (const float*)d_in[4];
    const int*   topk    = (const int*)d_in[5];
    float* out = (float*)d_out;
    float* ws  = (float*)d_ws;

    k3_dots<<<dim3((N + 255) / 256), dim3(256), 0, stream>>>(concept, te, ws);
    k1_gram_inv<<<dim3(1), dim3(1024), 0, stream>>>(concept, hxw, ws, out);
    k2_pred<<<dim3(B / 8), dim3(256), 0, stream>>>(concept, X, hxw, hxb, ws, out);
    k_init<<<dim3(C), dim3(256), 0, stream>>>(ws, topk);
    for (int pass = 0; pass < 3; ++pass) {
        k_hist<<<dim3(C, NCHUNK), dim3(256), 0, stream>>>(ws, ws, pass);
        k_pick<<<dim3(C), dim3(1024), 0, stream>>>(ws, pass);
    }
    k_fsum<<<dim3(C, NCHUNK), dim3(256), 0, stream>>>(ws, ws);
    k5_final<<<dim3(1), dim3(64), 0, stream>>>(ws, out, topk);
}